// Round 13
// baseline (2817.004 us; speedup 1.0000x reference)
//
#include <hip/hip_runtime.h>

typedef _Float16 half8 __attribute__((ext_vector_type(8)));
typedef float floatx4 __attribute__((ext_vector_type(4)));
typedef unsigned int uintx4 __attribute__((ext_vector_type(4)));

#define B_ 64
#define S_ 512
#define H_ 1024

// Arrival slots in .bss (zero at load; untouched by ws poison). Monotonic:
// each block's slot advances by exactly S_ per launch (init e0+1, then
// e0+t+2 for t=0..S_-2). Per-launch base e0 = own slot value read before any
// arrival (only the owner writes its slot; all slots equal at quiescence).
__device__ unsigned slotA[4][64];

__device__ __forceinline__ float sigmoidf_(float x) { return 1.0f / (1.0f + __expf(-x)); }
__device__ __forceinline__ float tanhf_(float x) {
    return 1.0f - 2.0f / (__expf(2.0f * x) + 1.0f);   // saturates correctly via __expf
}

// 256 blocks x 64 threads (ONE wave per block -- no __syncthreads anywhere).
// Block (cb=bid&63, mb=bid>>6) owns the 16x16 output tile: batches
// [16mb,16mb+16) x cols [16cb,16cb+16), FULL K=1024 in this single wave
// (96 MFMAs/step). No inter-wave K-reduce -> intra-block critical path is
// pure dataflow. B-fragments: gates W,U staged in LDS (64 KB; each lane
// reads back only what it wrote -> no cross-lane, no barrier, linear
// conflict-free layout); gate V persistent in 128 VGPRs.
//
// Protocol (r11-proven, minus barriers): publish = 4B packed sc1 stores
// (cols paired via shfl_xor) -> wave vmcnt(0) drain -> lane0 slot store.
// Wait = 64 lanes poll the group's 64 slots, __all. Payload read = 32
// forced inline-asm global_load_dwordx4 sc1 (single pipelined burst).
// WAR safety of the 2-deep xi buffer: passing poll(t) proves all 64 group
// blocks published step t, i.e. finished reading buffer[(t-1)&1]; a block
// writes buffer[(t+1)&1] (same one) only after its poll(t). Skew <= 1 step.
__global__ void __launch_bounds__(64, 1)
lstm_scan(const float* __restrict__ emb, const float* __restrict__ W, const float* __restrict__ bW,
          const float* __restrict__ U, const float* __restrict__ bU,
          const float* __restrict__ V, const float* __restrict__ bV,
          float* __restrict__ out, unsigned char* __restrict__ ws)
{
    const int bid  = blockIdx.x;
    const int cb   = bid & 63;    // column group (16 H-cols)
    const int mb   = bid >> 6;    // batch group (16 batches)
    const int lane = threadIdx.x; // single wave
    const int fr   = lane & 15;   // A-row / B-col fragment index
    const int kg   = lane >> 4;   // k-block fragment index

    unsigned*   pub32 = (unsigned*)ws;   // [2][64 rows][512] u32 (packed f16 pairs)
    const char* pubc  = (const char*)ws; // byte view for the asm burst

    // W,U B-fragments: [gate][ks][kg][n][8 f16] = 64 KB. Lane (kg,fr) writes
    // and later reads ONLY [*][*][kg][fr][*]: no cross-lane LDS traffic.
    // Read addr for fixed (gate,ks) = lane*16B -> linear, conflict-free.
    __shared__ _Float16 BL[2][32][4][16][8];

    const unsigned e0 = __hip_atomic_load(&slotA[mb][cb], __ATOMIC_RELAXED,
                                          __HIP_MEMORY_SCOPE_AGENT);

    // ---- stage B fragments: W,U -> LDS, V -> registers (one-time) ----
    // B[k][n] = Wgate[16cb + n][k]; lane (n=fr, kg) holds k = ks*32+kg*8+e.
    {
        const float* srcW = W + (cb * 16 + fr) * H_ + kg * 8;
        const float* srcU = U + (cb * 16 + fr) * H_ + kg * 8;
        #pragma unroll 4
        for (int ks = 0; ks < 32; ++ks) {
            float4 w0 = *(const float4*)(srcW + ks * 32);
            float4 w1 = *(const float4*)(srcW + ks * 32 + 4);
            float4 u0 = *(const float4*)(srcU + ks * 32);
            float4 u1 = *(const float4*)(srcU + ks * 32 + 4);
            half8 hw, hu;
            hw[0] = (_Float16)w0.x; hw[1] = (_Float16)w0.y; hw[2] = (_Float16)w0.z; hw[3] = (_Float16)w0.w;
            hw[4] = (_Float16)w1.x; hw[5] = (_Float16)w1.y; hw[6] = (_Float16)w1.z; hw[7] = (_Float16)w1.w;
            hu[0] = (_Float16)u0.x; hu[1] = (_Float16)u0.y; hu[2] = (_Float16)u0.z; hu[3] = (_Float16)u0.w;
            hu[4] = (_Float16)u1.x; hu[5] = (_Float16)u1.y; hu[6] = (_Float16)u1.z; hu[7] = (_Float16)u1.w;
            *(half8*)&BL[0][ks][kg][fr][0] = hw;
            *(half8*)&BL[1][ks][kg][fr][0] = hu;
        }
    }
    half8 Bfv[32];
    {
        const float* srcV = V + (cb * 16 + fr) * H_ + kg * 8;
        #pragma unroll
        for (int ks = 0; ks < 32; ++ks) {
            float4 v0 = *(const float4*)(srcV + ks * 32);
            float4 v1 = *(const float4*)(srcV + ks * 32 + 4);
            half8 hv;
            hv[0] = (_Float16)v0.x; hv[1] = (_Float16)v0.y; hv[2] = (_Float16)v0.z; hv[3] = (_Float16)v0.w;
            hv[4] = (_Float16)v1.x; hv[5] = (_Float16)v1.y; hv[6] = (_Float16)v1.z; hv[7] = (_Float16)v1.w;
            Bfv[ks] = hv;
        }
    }

    // ---- elementwise ownership: lane -> 4 cells (brow0+r, j) ----
    // C/D layout (proven): col = lane&15, row = (lane>>4)*4 + reg.
    const int j     = cb * 16 + fr;
    const int brow0 = mb * 16 + kg * 4;
    const float bw = bW[j], bu = bU[j], bv = bV[j];
    const bool evenfr = (fr & 1) == 0;

    auto publish = [&](int buf, unsigned slotval, const float* xin) {
        #pragma unroll
        for (int r = 0; r < 4; ++r) {
            union { _Float16 h; unsigned short u; } cvp; cvp.h = (_Float16)xin[r];
            unsigned mine  = cvp.u;
            unsigned other = (unsigned)__shfl_xor((int)mine, 1);
            if (evenfr)
                __hip_atomic_store(&pub32[(unsigned)(((buf * 64) + brow0 + r) * 512 + cb * 8 + (fr >> 1))],
                                   mine | (other << 16),
                                   __ATOMIC_RELAXED, __HIP_MEMORY_SCOPE_AGENT);
        }
        asm volatile("s_waitcnt vmcnt(0)" ::: "memory");   // all payload acked at LLC
        if (lane == 0)
            __hip_atomic_store(&slotA[mb][cb], slotval, __ATOMIC_RELAXED,
                               __HIP_MEMORY_SCOPE_AGENT);
    };

    auto waitall = [&](unsigned tgt) {
        for (;;) {
            unsigned v = __hip_atomic_load(&slotA[mb][lane], __ATOMIC_RELAXED,
                                           __HIP_MEMORY_SCOPE_AGENT);
            if (__all((int)(v - tgt) >= 0)) break;
            __builtin_amdgcn_s_sleep(1);
        }
        asm volatile("" ::: "memory");   // poll is a load barrier (and blocks LICM)
    };

    float p1s[4] = {0.f, 0.f, 0.f, 0.f};
    float xio[4], embn[4], xin[4];
    #pragma unroll
    for (int r = 0; r < 4; ++r) {
        xio[r] = emb[((brow0 + r) * S_ + 0) * H_ + j];   // p2 init = 0
        xin[r] = xio[r];
    }
    publish(0, e0 + 1u, xin);
    #pragma unroll
    for (int r = 0; r < 4; ++r) embn[r] = emb[((brow0 + r) * S_ + 1) * H_ + j];

    for (int t = 0; t < S_; ++t) {
        waitall(e0 + (unsigned)t + 1u);

        // ---- A burst: 512 B/lane = 32 forced dwordx4 sc1 (one round-trip) ----
        // lane's data: row (16mb+fr), k = ks*32 + kg*8 + [0,8), ks = 0..31
        const char* base = pubc + (unsigned)((((t & 1) * 64) + mb * 16 + fr) * 2048 + kg * 16);
        uintx4 q00,q01,q02,q03,q04,q05,q06,q07,q08,q09,q10,q11,q12,q13,q14,q15,
               q16,q17,q18,q19,q20,q21,q22,q23,q24,q25,q26,q27,q28,q29,q30,q31;
        asm volatile("global_load_dwordx4 %0, %1, off offset:0 sc1"    : "=v"(q00) : "v"(base));
        asm volatile("global_load_dwordx4 %0, %1, off offset:64 sc1"   : "=v"(q01) : "v"(base));
        asm volatile("global_load_dwordx4 %0, %1, off offset:128 sc1"  : "=v"(q02) : "v"(base));
        asm volatile("global_load_dwordx4 %0, %1, off offset:192 sc1"  : "=v"(q03) : "v"(base));
        asm volatile("global_load_dwordx4 %0, %1, off offset:256 sc1"  : "=v"(q04) : "v"(base));
        asm volatile("global_load_dwordx4 %0, %1, off offset:320 sc1"  : "=v"(q05) : "v"(base));
        asm volatile("global_load_dwordx4 %0, %1, off offset:384 sc1"  : "=v"(q06) : "v"(base));
        asm volatile("global_load_dwordx4 %0, %1, off offset:448 sc1"  : "=v"(q07) : "v"(base));
        asm volatile("global_load_dwordx4 %0, %1, off offset:512 sc1"  : "=v"(q08) : "v"(base));
        asm volatile("global_load_dwordx4 %0, %1, off offset:576 sc1"  : "=v"(q09) : "v"(base));
        asm volatile("global_load_dwordx4 %0, %1, off offset:640 sc1"  : "=v"(q10) : "v"(base));
        asm volatile("global_load_dwordx4 %0, %1, off offset:704 sc1"  : "=v"(q11) : "v"(base));
        asm volatile("global_load_dwordx4 %0, %1, off offset:768 sc1"  : "=v"(q12) : "v"(base));
        asm volatile("global_load_dwordx4 %0, %1, off offset:832 sc1"  : "=v"(q13) : "v"(base));
        asm volatile("global_load_dwordx4 %0, %1, off offset:896 sc1"  : "=v"(q14) : "v"(base));
        asm volatile("global_load_dwordx4 %0, %1, off offset:960 sc1"  : "=v"(q15) : "v"(base));
        asm volatile("global_load_dwordx4 %0, %1, off offset:1024 sc1" : "=v"(q16) : "v"(base));
        asm volatile("global_load_dwordx4 %0, %1, off offset:1088 sc1" : "=v"(q17) : "v"(base));
        asm volatile("global_load_dwordx4 %0, %1, off offset:1152 sc1" : "=v"(q18) : "v"(base));
        asm volatile("global_load_dwordx4 %0, %1, off offset:1216 sc1" : "=v"(q19) : "v"(base));
        asm volatile("global_load_dwordx4 %0, %1, off offset:1280 sc1" : "=v"(q20) : "v"(base));
        asm volatile("global_load_dwordx4 %0, %1, off offset:1344 sc1" : "=v"(q21) : "v"(base));
        asm volatile("global_load_dwordx4 %0, %1, off offset:1408 sc1" : "=v"(q22) : "v"(base));
        asm volatile("global_load_dwordx4 %0, %1, off offset:1472 sc1" : "=v"(q23) : "v"(base));
        asm volatile("global_load_dwordx4 %0, %1, off offset:1536 sc1" : "=v"(q24) : "v"(base));
        asm volatile("global_load_dwordx4 %0, %1, off offset:1600 sc1" : "=v"(q25) : "v"(base));
        asm volatile("global_load_dwordx4 %0, %1, off offset:1664 sc1" : "=v"(q26) : "v"(base));
        asm volatile("global_load_dwordx4 %0, %1, off offset:1728 sc1" : "=v"(q27) : "v"(base));
        asm volatile("global_load_dwordx4 %0, %1, off offset:1792 sc1" : "=v"(q28) : "v"(base));
        asm volatile("global_load_dwordx4 %0, %1, off offset:1856 sc1" : "=v"(q29) : "v"(base));
        asm volatile("global_load_dwordx4 %0, %1, off offset:1920 sc1" : "=v"(q30) : "v"(base));
        asm volatile("global_load_dwordx4 %0, %1, off offset:1984 sc1" : "=v"(q31) : "v"(base));
        asm volatile("s_waitcnt vmcnt(0)" ::: "memory");
        __builtin_amdgcn_sched_barrier(0);

        // ---- full-K MFMA: 32 ksteps x 3 gates, no inter-wave reduce ----
        floatx4 a0 = {0.f, 0.f, 0.f, 0.f};
        floatx4 a1 = {0.f, 0.f, 0.f, 0.f};
        floatx4 a2 = {0.f, 0.f, 0.f, 0.f};
        union { uintx4 v; half8 h; } cva;
        #define DO_KS(ks, Q)                                                        \
        {                                                                           \
            cva.v = Q; half8 Af = cva.h;                                            \
            a0 = __builtin_amdgcn_mfma_f32_16x16x32_f16(Af, *(const half8*)&BL[0][ks][kg][fr][0], a0, 0, 0, 0); \
            a1 = __builtin_amdgcn_mfma_f32_16x16x32_f16(Af, *(const half8*)&BL[1][ks][kg][fr][0], a1, 0, 0, 0); \
            a2 = __builtin_amdgcn_mfma_f32_16x16x32_f16(Af, Bfv[ks], a2, 0, 0, 0);  \
        }
        DO_KS( 0,q00) DO_KS( 1,q01) DO_KS( 2,q02) DO_KS( 3,q03)
        DO_KS( 4,q04) DO_KS( 5,q05) DO_KS( 6,q06) DO_KS( 7,q07)
        DO_KS( 8,q08) DO_KS( 9,q09) DO_KS(10,q10) DO_KS(11,q11)
        DO_KS(12,q12) DO_KS(13,q13) DO_KS(14,q14) DO_KS(15,q15)
        DO_KS(16,q16) DO_KS(17,q17) DO_KS(18,q18) DO_KS(19,q19)
        DO_KS(20,q20) DO_KS(21,q21) DO_KS(22,q22) DO_KS(23,q23)
        DO_KS(24,q24) DO_KS(25,q25) DO_KS(26,q26) DO_KS(27,q27)
        DO_KS(28,q28) DO_KS(29,q29) DO_KS(30,q30) DO_KS(31,q31)
        #undef DO_KS

        // ---- gates + state update (4 cells per lane, all in registers) ----
        float p2v[4];
        #pragma unroll
        for (int r = 0; r < 4; ++r) {
            float fg = sigmoidf_(a0[r] + bw);
            float ig = sigmoidf_(a1[r] + bu);
            float gg = tanhf_(a2[r] + bv);
            p1s[r] = fg * p1s[r] + ig * gg;
            p2v[r] = sigmoidf_(xio[r]) * tanhf_(p1s[r]);
        }

        if (t < S_ - 1) {
            #pragma unroll
            for (int r = 0; r < 4; ++r) { xin[r] = embn[r] + p2v[r]; xio[r] = xin[r]; }
            publish((t + 1) & 1, e0 + (unsigned)t + 2u, xin);
            // after the slot store: drain during other blocks' polls
            #pragma unroll
            for (int r = 0; r < 4; ++r) {
                __builtin_nontemporal_store(p2v[r], &out[((brow0 + r) * S_ + t) * H_ + j]);
                if (t + 2 < S_) embn[r] = emb[((brow0 + r) * S_ + t + 2) * H_ + j];
            }
        } else {
            #pragma unroll
            for (int r = 0; r < 4; ++r)
                __builtin_nontemporal_store(p2v[r], &out[((brow0 + r) * S_ + t) * H_ + j]);
        }
    }
}

extern "C" void kernel_launch(void* const* d_in, const int* in_sizes, int n_in,
                              void* d_out, int out_size, void* d_ws, size_t ws_size,
                              hipStream_t stream)
{
    const float* emb = (const float*)d_in[0];
    const float* W   = (const float*)d_in[1];
    const float* bWv = (const float*)d_in[2];
    const float* U   = (const float*)d_in[3];
    const float* bUv = (const float*)d_in[4];
    const float* V   = (const float*)d_in[5];
    const float* bVv = (const float*)d_in[6];
    float* outp = (float*)d_out;
    unsigned char* ws = (unsigned char*)d_ws;
    (void)in_sizes; (void)n_in; (void)out_size; (void)ws_size;

    void* args[] = {(void*)&emb, (void*)&W, (void*)&bWv, (void*)&U, (void*)&bUv,
                    (void*)&V, (void*)&bVv, (void*)&outp, (void*)&ws};
    hipError_t err = hipLaunchCooperativeKernel((const void*)lstm_scan,
                                                dim3(256), dim3(64), args, 0, stream);
    if (err != hipSuccess) {
        // r2/r3 lesson: cooperative launch can fail silently for envelope
        // reasons. Fall back to a plain launch (identical semantics; 256
        // single-wave blocks are co-resident at 1-2 blocks/CU).
        lstm_scan<<<dim3(256), dim3(64), 0, stream>>>(emb, W, bWv, U, bUv, V, bVv, outp, ws);
    }
}